// Round 6
// baseline (341.333 us; speedup 1.0000x reference)
//
#include <hip/hip_runtime.h>
#include <hip/hip_bf16.h>

#define BATCH 2
#define SEQ 2048
#define HID 2048
#define NH 32
#define NKVH 8
#define HD 64
#define GQ 4
#define ROT 32

typedef __attribute__((ext_vector_type(8))) short bf16x8;
typedef __attribute__((ext_vector_type(8))) unsigned short u16x8;
typedef __attribute__((ext_vector_type(4))) float f32x4;
typedef unsigned int u32;
typedef unsigned short u16;

#define MFMA_BF16(A, B, C) __builtin_amdgcn_mfma_f32_16x16x32_bf16(A, B, C, 0, 0, 0)

// 0.125 (1/sqrt(64)) * log2(e): folded into Q at projection time
#define QSCALE 0.180336880111120f

__device__ __forceinline__ void gload_lds16(const void* g, void* l) {
    __builtin_amdgcn_global_load_lds(
        (const __attribute__((address_space(1))) unsigned int*)g,
        (__attribute__((address_space(3))) unsigned int*)l, 16, 0, 0);
}

__device__ __forceinline__ u16 f2b(float x) {
    union { __hip_bfloat16 h; u16 u; } cv;
    cv.h = __float2bfloat16(x);
    return cv.u;
}
// round-half-up bf16x2 pack: (hi|lo) in 3 VALU ops (values finite, non-NaN)
__device__ __forceinline__ u32 pack2r(float lo, float hi) {
    u32 a = __builtin_bit_cast(u32, lo) + 0x8000u;
    u32 b = __builtin_bit_cast(u32, hi) + 0x8000u;
    return __builtin_amdgcn_perm(b, a, 0x07060302u);
}

// ---------------------------------------------------------------------------
// One fused cast dispatch: hs, Wq, Wk, Wv, Wo -> bf16. 2048 elems per block.
// ---------------------------------------------------------------------------
__global__ __launch_bounds__(256) void cast_all(
    const float* __restrict__ hs, const float* __restrict__ Wq,
    const float* __restrict__ Wk, const float* __restrict__ Wv,
    const float* __restrict__ Wo, u16* __restrict__ d_hs, u16* __restrict__ d_Wq,
    u16* __restrict__ d_Wk, u16* __restrict__ d_Wv, u16* __restrict__ d_Wo) {
    const int bx = blockIdx.x;
    const float* s;
    u16* d;
    int off;
    if (bx < 4096) { s = hs; d = d_hs; off = bx; }
    else if (bx < 6144) { s = Wq; d = d_Wq; off = bx - 4096; }
    else if (bx < 6656) { s = Wk; d = d_Wk; off = bx - 6144; }
    else if (bx < 7168) { s = Wv; d = d_Wv; off = bx - 6656; }
    else { s = Wo; d = d_Wo; off = bx - 7168; }
    const size_t i = (size_t)off * 2048 + threadIdx.x * 8;
    const float4 a = *(const float4*)&s[i];
    const float4 b = *(const float4*)&s[i + 4];
    u16x8 v;
    v[0] = f2b(a.x); v[1] = f2b(a.y); v[2] = f2b(a.z); v[3] = f2b(a.w);
    v[4] = f2b(b.x); v[5] = f2b(b.y); v[6] = f2b(b.z); v[7] = f2b(b.w);
    *(u16x8*)&d[i] = v;
}

// ---------------------------------------------------------------------------
// Fused QKV projection. 128x128 tiles, BK=32, 4 waves, 16x16x32 MFMA.
// 1D grid, XCD-swizzled: xcd=bid&7 owns n-tiles [3*xcd,3*xcd+3), m fastest ->
// W tiles stay L2-resident per XCD, A rows L2-hot within a 3-block burst.
// n-tile: [0,16) Q (+rope +QSCALE), [16,20) K (+rope), [20,24) V (-> Vt).
// Q/K use SWAPPED MFMA operands (C^T in regs): lane owns 4 consecutive d ->
// 8B stores; RoPE pair (d,d+16) register-local; cos/sin are float4 loads.
// V unswapped: lane owns 4 consecutive tokens -> 8B stores into Vt[d][s].
// ---------------------------------------------------------------------------
__global__ __launch_bounds__(256) void qkv_gemm(
    const u16* __restrict__ A, const u16* __restrict__ Wq,
    const u16* __restrict__ Wk, const u16* __restrict__ Wv,
    u16* __restrict__ Qb, u16* __restrict__ Kb, u16* __restrict__ Vt,
    const float* __restrict__ cosp, const float* __restrict__ sinp) {
    const int bid = blockIdx.x;
    const int xcd = bid & 7, loc = bid >> 3;   // 96 locals per xcd
    const int x = xcd * 3 + (loc % 3);         // n-tile 0..23
    const int m0 = (loc / 3) * 128;

    int mode, n0;
    const u16* __restrict__ W;
    if (x < 16)      { mode = 0; W = Wq; n0 = x * 128; }
    else if (x < 20) { mode = 1; W = Wk; n0 = (x - 16) * 128; }
    else             { mode = 2; W = Wv; n0 = (x - 20) * 128; }

    __shared__ __align__(16) u16 As[128 * 32];
    __shared__ __align__(16) u16 Ws[128 * 32];
    const int tid = threadIdx.x;
    const int lane = tid & 63, wave = tid >> 6;
    const int ar = lane & 15, quad = lane >> 4;
    const int q4 = quad * 4;
    const int wm = (wave >> 1) * 64, wn = (wave & 1) * 64;

    f32x4 acc[4][4] = {};

    for (int k0 = 0; k0 < HID; k0 += 32) {
#pragma unroll
        for (int it = 0; it < 2; ++it) {
            const int ci = it * 256 + tid;
            const int row = ci >> 2, kcl = ci & 3;
            const int kcg = kcl ^ ((row >> 1) & 3);
            gload_lds16(&A[(size_t)(m0 + row) * HID + k0 + kcg * 8], &As[ci * 8]);
            gload_lds16(&W[(size_t)(n0 + row) * HID + k0 + kcg * 8], &Ws[ci * 8]);
        }
        __syncthreads();
        bf16x8 af[4], bf[4];
#pragma unroll
        for (int t = 0; t < 4; ++t) {
            const int ra = wm + t * 16 + ar;
            af[t] = *(const bf16x8*)&As[ra * 32 + (quad ^ ((ra >> 1) & 3)) * 8];
            const int rb = wn + t * 16 + ar;
            bf[t] = *(const bf16x8*)&Ws[rb * 32 + (quad ^ ((rb >> 1) & 3)) * 8];
        }
        if (mode < 2) {  // swapped: acc = W_tile * A_tile^T  (C^T layout)
#pragma unroll
            for (int mt = 0; mt < 4; ++mt)
#pragma unroll
                for (int nt = 0; nt < 4; ++nt)
                    acc[mt][nt] = MFMA_BF16(bf[nt], af[mt], acc[mt][nt]);
        } else {
#pragma unroll
            for (int mt = 0; mt < 4; ++mt)
#pragma unroll
                for (int nt = 0; nt < 4; ++nt)
                    acc[mt][nt] = MFMA_BF16(af[mt], bf[nt], acc[mt][nt]);
        }
        __syncthreads();
    }

    if (mode < 2) {
        // C^T regs: acc[mt][nt][r] = C[token = m0+wm+mt*16+ar][n = wn+nt*16+q4+r]
        const float SC = (mode == 0) ? QSCALE : 1.0f;
        u16* __restrict__ C = (mode == 0) ? Qb : Kb;
        const int N = (mode == 0) ? 2048 : 512;
#pragma unroll
        for (int mt = 0; mt < 4; ++mt) {
            const int t = m0 + wm + mt * 16 + ar;
            const float4 c0 = *(const float4*)&cosp[(size_t)t * ROT + q4];
            const float4 s0 = *(const float4*)&sinp[(size_t)t * ROT + q4];
            const float4 c1 = *(const float4*)&cosp[(size_t)t * ROT + 16 + q4];
            const float4 s1 = *(const float4*)&sinp[(size_t)t * ROT + 16 + q4];
            u16* crow = &C[(size_t)t * N + n0 + wn];
            const f32x4 x0 = acc[mt][0], x1 = acc[mt][1];
            const float cr0[4] = {c0.x, c0.y, c0.z, c0.w};
            const float sr0[4] = {s0.x, s0.y, s0.z, s0.w};
            const float cr1[4] = {c1.x, c1.y, c1.z, c1.w};
            const float sr1[4] = {s1.x, s1.y, s1.z, s1.w};
            float o0[4], o1[4];
#pragma unroll
            for (int r = 0; r < 4; ++r) {
                o0[r] = (x0[r] * cr0[r] - x1[r] * sr0[r]) * SC;
                o1[r] = (x1[r] * cr1[r] + x0[r] * sr1[r]) * SC;
            }
            uint2 v;
            v.x = pack2r(o0[0], o0[1]); v.y = pack2r(o0[2], o0[3]);
            *(uint2*)&crow[q4] = v;
            v.x = pack2r(o1[0], o1[1]); v.y = pack2r(o1[2], o1[3]);
            *(uint2*)&crow[16 + q4] = v;
            v.x = pack2r(acc[mt][2][0] * SC, acc[mt][2][1] * SC);
            v.y = pack2r(acc[mt][2][2] * SC, acc[mt][2][3] * SC);
            *(uint2*)&crow[32 + q4] = v;
            v.x = pack2r(acc[mt][3][0] * SC, acc[mt][3][1] * SC);
            v.y = pack2r(acc[mt][3][2] * SC, acc[mt][3][3] * SC);
            *(uint2*)&crow[48 + q4] = v;
        }
    } else {
        // V epilogue (unswapped): Vt[(b*NKVH+kvh)*HD + d][s with pi relabeling]
#pragma unroll
        for (int mt = 0; mt < 4; ++mt) {
            const int r0 = m0 + wm + mt * 16 + q4;  // token, %4==0
            const int bb = r0 >> 11;
            const int s = r0 & 2047;
            const int ca = (s >> 2) & 7;
            const int cl = ((ca & 3) << 1) | (ca >> 2);
            const int spos = (s & ~31) + cl * 4;
#pragma unroll
            for (int nt = 0; nt < 4; ++nt) {
                const int c = n0 + wn + nt * 16 + ar;
                const int kvh = c >> 6, d = c & 63;
                uint2 v;
                v.x = pack2r(acc[mt][nt][0], acc[mt][nt][1]);
                v.y = pack2r(acc[mt][nt][2], acc[mt][nt][3]);
                *(uint2*)&Vt[((size_t)(bb * NKVH + kvh) * HD + d) * SEQ + spos] = v;
            }
        }
    }
}

// ---------------------------------------------------------------------------
// O projection: C[M,N] = A[M,K] @ W[N,K]^T, fp32 out. Swapped operands ->
// lane owns 4 consecutive n -> float4 stores. XCD swizzle: xcd owns 2 n-tiles.
// ---------------------------------------------------------------------------
__global__ __launch_bounds__(256) void gemm_bt(const u16* __restrict__ A,
                                               const u16* __restrict__ W,
                                               float* __restrict__ C,
                                               int M, int N, int K) {
    const int bid = blockIdx.x;
    const int xcd = bid & 7, loc = bid >> 3;   // 64 locals per xcd
    const int n0 = (xcd * 2 + (loc & 1)) * 128;
    const int m0 = (loc >> 1) * 128;

    __shared__ __align__(16) u16 As[128 * 32];
    __shared__ __align__(16) u16 Ws[128 * 32];
    const int tid = threadIdx.x;
    const int lane = tid & 63, wave = tid >> 6;
    const int ar = lane & 15, quad = lane >> 4;
    const int q4 = quad * 4;
    const int wm = (wave >> 1) * 64, wn = (wave & 1) * 64;

    f32x4 acc[4][4] = {};

    for (int k0 = 0; k0 < K; k0 += 32) {
#pragma unroll
        for (int it = 0; it < 2; ++it) {
            const int ci = it * 256 + tid;
            const int row = ci >> 2, kcl = ci & 3;
            const int kcg = kcl ^ ((row >> 1) & 3);
            gload_lds16(&A[(size_t)(m0 + row) * K + k0 + kcg * 8], &As[ci * 8]);
            gload_lds16(&W[(size_t)(n0 + row) * K + k0 + kcg * 8], &Ws[ci * 8]);
        }
        __syncthreads();
        bf16x8 af[4], bf[4];
#pragma unroll
        for (int t = 0; t < 4; ++t) {
            const int ra = wm + t * 16 + ar;
            af[t] = *(const bf16x8*)&As[ra * 32 + (quad ^ ((ra >> 1) & 3)) * 8];
            const int rb = wn + t * 16 + ar;
            bf[t] = *(const bf16x8*)&Ws[rb * 32 + (quad ^ ((rb >> 1) & 3)) * 8];
        }
#pragma unroll
        for (int mt = 0; mt < 4; ++mt)
#pragma unroll
            for (int nt = 0; nt < 4; ++nt)
                acc[mt][nt] = MFMA_BF16(bf[nt], af[mt], acc[mt][nt]);  // C^T
        __syncthreads();
    }

    // C^T regs: acc[mt][nt][r] = C[m0+wm+mt*16+ar][n0+wn+nt*16+q4+r]
#pragma unroll
    for (int mt = 0; mt < 4; ++mt) {
        const int t = m0 + wm + mt * 16 + ar;
#pragma unroll
        for (int nt = 0; nt < 4; ++nt) {
            float4 v = {acc[mt][nt][0], acc[mt][nt][1], acc[mt][nt][2], acc[mt][nt][3]};
            *(float4*)&C[(size_t)t * N + n0 + wn + nt * 16 + q4] = v;
        }
    }
}

// ---------------------------------------------------------------------------
// Flash attention, S^T formulation, causal-balanced: block p handles q-tiles
// p and 15-p (uniform 34 kv-iters). 128 q rows per phase, 32/wave.
// S^T = K*Q^T (lane owns q); O^T = V^T*P^T (own post-exp regs ARE the P^T
// B-frag under the kv relabeling baked into Vt). Max-free streaming softmax.
// ---------------------------------------------------------------------------
__global__ __launch_bounds__(256, 2) void flash_attn_mfma(
    const u16* __restrict__ Qg, const u16* __restrict__ Kg,
    const u16* __restrict__ Vtg, u16* __restrict__ AO) {
    const int p = blockIdx.x, h = blockIdx.y, b = blockIdx.z;
    const int kvh = h / GQ;
    const int tid = threadIdx.x;
    const int lane = tid & 63, w = tid >> 6;
    const int n = lane & 15, quad = lane >> 4;

    __shared__ __align__(16) u16 Qs[128 * 64];
    __shared__ __align__(16) u16 Ks[2 * 64 * 64];
    __shared__ __align__(16) u16 Vts[2 * 64 * 64];

    for (int ph = 0; ph < 2; ++ph) {
        const int bq = ph ? (15 - p) : p;
        const int q0 = bq * 128;

        // stage Q (128x64) and K/V tile 0 into buffer 0 (chunk ^= row&7)
#pragma unroll
        for (int it = 0; it < 4; ++it) {
            const int ci = it * 256 + tid;
            const int row = ci >> 3, kcg = (ci & 7) ^ (row & 7);
            gload_lds16(&Qg[(size_t)((b * SEQ + q0 + row) * NH + h) * HD + kcg * 8],
                        &Qs[ci * 8]);
        }
#pragma unroll
        for (int it = 0; it < 2; ++it) {
            const int ci = it * 256 + tid;
            const int row = ci >> 3, kcg = (ci & 7) ^ (row & 7);
            gload_lds16(&Kg[(size_t)((b * SEQ + row) * NKVH + kvh) * HD + kcg * 8],
                        &Ks[ci * 8]);
            gload_lds16(&Vtg[(size_t)((b * NKVH + kvh) * HD + row) * SEQ + kcg * 8],
                        &Vts[ci * 8]);
        }
        __syncthreads();

        // hoist Q^T B-frags
        bf16x8 Qf[2][2];
#pragma unroll
        for (int t = 0; t < 2; ++t)
#pragma unroll
            for (int kh = 0; kh < 2; ++kh) {
                const int qrow = w * 32 + t * 16 + n;
                const int c = (kh * 4 + quad) ^ (qrow & 7);
                Qf[t][kh] = *(const bf16x8*)&Qs[qrow * 64 + c * 8];
            }

        f32x4 O[2][4] = {};
        float lsum[2] = {0.f, 0.f};

        const int ktmax = 2 * bq + 1;
        for (int kt = 0; kt <= ktmax; ++kt) {
            const int cur = kt & 1;
            if (kt < ktmax) {  // prefetch next K/V tile into other buffer
                const int base = (cur ^ 1) * 4096;
#pragma unroll
                for (int it = 0; it < 2; ++it) {
                    const int ci = it * 256 + tid;
                    const int row = ci >> 3, kcg = (ci & 7) ^ (row & 7);
                    gload_lds16(&Kg[(size_t)((b * SEQ + (kt + 1) * 64 + row) * NKVH + kvh) * HD + kcg * 8],
                                &Ks[base + ci * 8]);
                    gload_lds16(&Vtg[(size_t)((b * NKVH + kvh) * HD + row) * SEQ + (kt + 1) * 64 + kcg * 8],
                                &Vts[base + ci * 8]);
                }
            }
            const u16* Kl = &Ks[cur * 4096];
            const u16* Vl = &Vts[cur * 4096];

            // S^T (log2-scaled domain; Q pre-scaled)
            f32x4 sc[2][4] = {};
#pragma unroll
            for (int kh = 0; kh < 2; ++kh)
#pragma unroll
                for (int k4 = 0; k4 < 4; ++k4) {
                    const int krow = k4 * 16 + n;
                    const int c = (kh * 4 + quad) ^ (krow & 7);
                    const bf16x8 Kf = *(const bf16x8*)&Kl[krow * 64 + c * 8];
                    sc[0][k4] = MFMA_BF16(Kf, Qf[0][kh], sc[0][k4]);
                    sc[1][k4] = MFMA_BF16(Kf, Qf[1][kh], sc[1][k4]);
                }

            const bool masked = (kt >= 2 * bq);
            bf16x8 Pf[2][2];
#pragma unroll
            for (int t = 0; t < 2; ++t) {
                const int qg = q0 + w * 32 + t * 16 + n;
                if (masked) {
#pragma unroll
                    for (int k4 = 0; k4 < 4; ++k4)
#pragma unroll
                        for (int r = 0; r < 4; ++r)
                            if (kt * 64 + k4 * 16 + quad * 4 + r > qg)
                                sc[t][k4][r] = -1e30f;  // exp2 -> 0
                }
                float sk[4];
#pragma unroll
                for (int k4 = 0; k4 < 4; ++k4) {
                    const float e0 = exp2f(sc[t][k4][0]);
                    const float e1 = exp2f(sc[t][k4][1]);
                    const float e2 = exp2f(sc[t][k4][2]);
                    const float e3 = exp2f(sc[t][k4][3]);
                    sc[t][k4][0] = e0; sc[t][k4][1] = e1;
                    sc[t][k4][2] = e2; sc[t][k4][3] = e3;
                    sk[k4] = (e0 + e1) + (e2 + e3);
                }
                lsum[t] += (sk[0] + sk[1]) + (sk[2] + sk[3]);
#pragma unroll
                for (int kb = 0; kb < 2; ++kb) {
                    union { u32 uw[4]; bf16x8 v; } cv;
#pragma unroll
                    for (int a = 0; a < 2; ++a) {
                        cv.uw[a * 2 + 0] = pack2r(sc[t][2 * kb + a][0], sc[t][2 * kb + a][1]);
                        cv.uw[a * 2 + 1] = pack2r(sc[t][2 * kb + a][2], sc[t][2 * kb + a][3]);
                    }
                    Pf[t][kb] = cv.v;
                }
            }

            // O^T += V^T * P^T
#pragma unroll
            for (int kb = 0; kb < 2; ++kb)
#pragma unroll
                for (int dt = 0; dt < 4; ++dt) {
                    const int drow = dt * 16 + n;
                    const int c = (kb * 4 + quad) ^ (drow & 7);
                    const bf16x8 Vf = *(const bf16x8*)&Vl[drow * 64 + c * 8];
                    O[0][dt] = MFMA_BF16(Vf, Pf[0][kb], O[0][dt]);
                    O[1][dt] = MFMA_BF16(Vf, Pf[1][kb], O[1][dt]);
                }
            __syncthreads();
        }

        // epilogue: reduce l across quads once; O^T regs: d=dt*16+quad*4+r, q=n
#pragma unroll
        for (int t = 0; t < 2; ++t) {
            float rs = lsum[t];
            rs += __shfl_xor(rs, 16, 64);
            rs += __shfl_xor(rs, 32, 64);
            const int qg = q0 + w * 32 + t * 16 + n;
            const float inv = 1.f / rs;
#pragma unroll
            for (int dt = 0; dt < 4; ++dt) {
                uint2 v2;
                v2.x = pack2r(O[t][dt][0] * inv, O[t][dt][1] * inv);
                v2.y = pack2r(O[t][dt][2] * inv, O[t][dt][3] * inv);
                *(uint2*)&AO[(size_t)((b * SEQ + qg) * NH + h) * HD + dt * 16 + quad * 4] = v2;
            }
        }
    }
}

// ---------------------------------------------------------------------------
extern "C" void kernel_launch(void* const* d_in, const int* in_sizes, int n_in,
                              void* d_out, int out_size, void* d_ws,
                              size_t ws_size, hipStream_t stream) {
    const float* hs = (const float*)d_in[0];
    const float* cosp = (const float*)d_in[1];
    const float* sinp = (const float*)d_in[2];
    // d_in[3] attention_mask: pure causal, handled in-kernel
    const float* Wq = (const float*)d_in[4];
    const float* Wk = (const float*)d_in[5];
    const float* Wv = (const float*)d_in[6];
    const float* Wo = (const float*)d_in[7];
    float* out = (float*)d_out;

    u16* ws = (u16*)d_ws;
    u16* hs_bf = ws;
    u16* Wq_bf = hs_bf + (size_t)4096 * 2048;
    u16* Wk_bf = Wq_bf + (size_t)2048 * 2048;
    u16* Wv_bf = Wk_bf + (size_t)512 * 2048;
    u16* Wo_bf = Wv_bf + (size_t)512 * 2048;
    u16* Qb = Wo_bf + (size_t)2048 * 2048;
    u16* Kb = Qb + (size_t)4096 * 2048;
    u16* Vt = Kb + (size_t)4096 * 512;
    u16* AO = hs_bf;  // alias: hs_bf dead after QKV projection

    cast_all<<<dim3(9216), 256, 0, stream>>>(hs, Wq, Wk, Wv, Wo, hs_bf, Wq_bf,
                                             Wk_bf, Wv_bf, Wo_bf);

    qkv_gemm<<<dim3(768), 256, 0, stream>>>(hs_bf, Wq_bf, Wk_bf, Wv_bf, Qb,
                                            Kb, Vt, cosp, sinp);

    flash_attn_mfma<<<dim3(8, NH, BATCH), 256, 0, stream>>>(Qb, Kb, Vt, AO);

    gemm_bt<<<dim3(512), 256, 0, stream>>>(AO, Wo_bf, out, 4096, 2048, 2048);
}

// Round 7
// 312.767 us; speedup vs baseline: 1.0913x; 1.0913x over previous
//
#include <hip/hip_runtime.h>
#include <hip/hip_bf16.h>

#define BATCH 2
#define SEQ 2048
#define HID 2048
#define NH 32
#define NKVH 8
#define HD 64
#define GQ 4
#define ROT 32

typedef __attribute__((ext_vector_type(8))) short bf16x8;
typedef __attribute__((ext_vector_type(8))) unsigned short u16x8;
typedef __attribute__((ext_vector_type(4))) float f32x4;
typedef unsigned int u32;
typedef unsigned short u16;

#define MFMA_BF16(A, B, C) __builtin_amdgcn_mfma_f32_16x16x32_bf16(A, B, C, 0, 0, 0)

// 0.125 (1/sqrt(64)) * log2(e): folded into Q at projection time
#define QSCALE 0.180336880111120f

__device__ __forceinline__ void gload_lds16(const void* g, void* l) {
    __builtin_amdgcn_global_load_lds(
        (const __attribute__((address_space(1))) unsigned int*)g,
        (__attribute__((address_space(3))) unsigned int*)l, 16, 0, 0);
}

__device__ __forceinline__ u16 f2b(float x) {
    union { __hip_bfloat16 h; u16 u; } cv;
    cv.h = __float2bfloat16(x);
    return cv.u;
}
// round-half-up bf16x2 pack: (hi|lo) in 3 VALU ops (values finite, non-NaN)
__device__ __forceinline__ u32 pack2r(float lo, float hi) {
    u32 a = __builtin_bit_cast(u32, lo) + 0x8000u;
    u32 b = __builtin_bit_cast(u32, hi) + 0x8000u;
    return __builtin_amdgcn_perm(b, a, 0x07060302u);
}

// ---------------------------------------------------------------------------
// One fused cast dispatch: hs, Wq, Wk, Wv, Wo -> bf16. 2048 elems per block.
// ---------------------------------------------------------------------------
__global__ __launch_bounds__(256) void cast_all(
    const float* __restrict__ hs, const float* __restrict__ Wq,
    const float* __restrict__ Wk, const float* __restrict__ Wv,
    const float* __restrict__ Wo, u16* __restrict__ d_hs, u16* __restrict__ d_Wq,
    u16* __restrict__ d_Wk, u16* __restrict__ d_Wv, u16* __restrict__ d_Wo) {
    const int bx = blockIdx.x;
    const float* s;
    u16* d;
    int off;
    if (bx < 4096) { s = hs; d = d_hs; off = bx; }
    else if (bx < 6144) { s = Wq; d = d_Wq; off = bx - 4096; }
    else if (bx < 6656) { s = Wk; d = d_Wk; off = bx - 6144; }
    else if (bx < 7168) { s = Wv; d = d_Wv; off = bx - 6656; }
    else { s = Wo; d = d_Wo; off = bx - 7168; }
    const size_t i = (size_t)off * 2048 + threadIdx.x * 8;
    const float4 a = *(const float4*)&s[i];
    const float4 b = *(const float4*)&s[i + 4];
    u16x8 v;
    v[0] = f2b(a.x); v[1] = f2b(a.y); v[2] = f2b(a.z); v[3] = f2b(a.w);
    v[4] = f2b(b.x); v[5] = f2b(b.y); v[6] = f2b(b.z); v[7] = f2b(b.w);
    *(u16x8*)&d[i] = v;
}

// ---------------------------------------------------------------------------
// Fused QKV projection. 128x128 tiles, BK=64 (32 barriers instead of 64 —
// the vmcnt(0)+s_barrier drain per iter is the structural stall; halve its
// count), 4 waves, 16x16x32 MFMA. 1D grid, XCD-swizzled.
// n-tile: [0,16) Q (+rope +QSCALE), [16,20) K (+rope), [20,24) V (-> Vt).
// Q/K use SWAPPED MFMA operands (C^T in regs): lane owns 4 consecutive d ->
// 8B stores; RoPE pair (d,d+16) register-local. V unswapped -> Vt[d][s].
// ---------------------------------------------------------------------------
__global__ __launch_bounds__(256) void qkv_gemm(
    const u16* __restrict__ A, const u16* __restrict__ Wq,
    const u16* __restrict__ Wk, const u16* __restrict__ Wv,
    u16* __restrict__ Qb, u16* __restrict__ Kb, u16* __restrict__ Vt,
    const float* __restrict__ cosp, const float* __restrict__ sinp) {
    const int bid = blockIdx.x;
    const int xcd = bid & 7, loc = bid >> 3;   // 96 locals per xcd
    const int x = xcd * 3 + (loc % 3);         // n-tile 0..23
    const int m0 = (loc / 3) * 128;

    int mode, n0;
    const u16* __restrict__ W;
    if (x < 16)      { mode = 0; W = Wq; n0 = x * 128; }
    else if (x < 20) { mode = 1; W = Wk; n0 = (x - 16) * 128; }
    else             { mode = 2; W = Wv; n0 = (x - 20) * 128; }

    __shared__ __align__(16) u16 As[128 * 64];
    __shared__ __align__(16) u16 Ws[128 * 64];
    const int tid = threadIdx.x;
    const int lane = tid & 63, wave = tid >> 6;
    const int ar = lane & 15, quad = lane >> 4;
    const int q4 = quad * 4;
    const int wm = (wave >> 1) * 64, wn = (wave & 1) * 64;

    f32x4 acc[4][4] = {};

    for (int k0 = 0; k0 < HID; k0 += 64) {
#pragma unroll
        for (int it = 0; it < 4; ++it) {
            const int ci = it * 256 + tid;     // 16B chunk, 1024 per matrix
            const int row = ci >> 3, kcl = ci & 7;
            const int kcg = kcl ^ (row & 7);
            gload_lds16(&A[(size_t)(m0 + row) * HID + k0 + kcg * 8], &As[ci * 8]);
            gload_lds16(&W[(size_t)(n0 + row) * HID + k0 + kcg * 8], &Ws[ci * 8]);
        }
        __syncthreads();
#pragma unroll
        for (int kh = 0; kh < 2; ++kh) {
            bf16x8 af[4], bf[4];
#pragma unroll
            for (int t = 0; t < 4; ++t) {
                const int ra = wm + t * 16 + ar;
                af[t] = *(const bf16x8*)&As[ra * 64 + (((kh * 4 + quad) ^ (ra & 7))) * 8];
                const int rb = wn + t * 16 + ar;
                bf[t] = *(const bf16x8*)&Ws[rb * 64 + (((kh * 4 + quad) ^ (rb & 7))) * 8];
            }
            if (mode < 2) {  // swapped: acc = W_tile * A_tile^T  (C^T layout)
#pragma unroll
                for (int mt = 0; mt < 4; ++mt)
#pragma unroll
                    for (int nt = 0; nt < 4; ++nt)
                        acc[mt][nt] = MFMA_BF16(bf[nt], af[mt], acc[mt][nt]);
            } else {
#pragma unroll
                for (int mt = 0; mt < 4; ++mt)
#pragma unroll
                    for (int nt = 0; nt < 4; ++nt)
                        acc[mt][nt] = MFMA_BF16(af[mt], bf[nt], acc[mt][nt]);
            }
        }
        __syncthreads();
    }

    if (mode < 2) {
        // C^T regs: acc[mt][nt][r] = C[token = m0+wm+mt*16+ar][n = wn+nt*16+q4+r]
        const float SC = (mode == 0) ? QSCALE : 1.0f;
        u16* __restrict__ C = (mode == 0) ? Qb : Kb;
        const int N = (mode == 0) ? 2048 : 512;
#pragma unroll
        for (int mt = 0; mt < 4; ++mt) {
            const int t = m0 + wm + mt * 16 + ar;
            const float4 c0 = *(const float4*)&cosp[(size_t)t * ROT + q4];
            const float4 s0 = *(const float4*)&sinp[(size_t)t * ROT + q4];
            const float4 c1 = *(const float4*)&cosp[(size_t)t * ROT + 16 + q4];
            const float4 s1 = *(const float4*)&sinp[(size_t)t * ROT + 16 + q4];
            u16* crow = &C[(size_t)t * N + n0 + wn];
            const f32x4 x0 = acc[mt][0], x1 = acc[mt][1];
            const float cr0[4] = {c0.x, c0.y, c0.z, c0.w};
            const float sr0[4] = {s0.x, s0.y, s0.z, s0.w};
            const float cr1[4] = {c1.x, c1.y, c1.z, c1.w};
            const float sr1[4] = {s1.x, s1.y, s1.z, s1.w};
            float o0[4], o1[4];
#pragma unroll
            for (int r = 0; r < 4; ++r) {
                o0[r] = (x0[r] * cr0[r] - x1[r] * sr0[r]) * SC;
                o1[r] = (x1[r] * cr1[r] + x0[r] * sr1[r]) * SC;
            }
            uint2 v;
            v.x = pack2r(o0[0], o0[1]); v.y = pack2r(o0[2], o0[3]);
            *(uint2*)&crow[q4] = v;
            v.x = pack2r(o1[0], o1[1]); v.y = pack2r(o1[2], o1[3]);
            *(uint2*)&crow[16 + q4] = v;
            v.x = pack2r(acc[mt][2][0] * SC, acc[mt][2][1] * SC);
            v.y = pack2r(acc[mt][2][2] * SC, acc[mt][2][3] * SC);
            *(uint2*)&crow[32 + q4] = v;
            v.x = pack2r(acc[mt][3][0] * SC, acc[mt][3][1] * SC);
            v.y = pack2r(acc[mt][3][2] * SC, acc[mt][3][3] * SC);
            *(uint2*)&crow[48 + q4] = v;
        }
    } else {
        // V epilogue (unswapped): Vt[(b*NKVH+kvh)*HD + d][s with pi relabeling]
#pragma unroll
        for (int mt = 0; mt < 4; ++mt) {
            const int r0 = m0 + wm + mt * 16 + q4;  // token, %4==0
            const int bb = r0 >> 11;
            const int s = r0 & 2047;
            const int ca = (s >> 2) & 7;
            const int cl = ((ca & 3) << 1) | (ca >> 2);
            const int spos = (s & ~31) + cl * 4;
#pragma unroll
            for (int nt = 0; nt < 4; ++nt) {
                const int c = n0 + wn + nt * 16 + ar;
                const int kvh = c >> 6, d = c & 63;
                uint2 v;
                v.x = pack2r(acc[mt][nt][0], acc[mt][nt][1]);
                v.y = pack2r(acc[mt][nt][2], acc[mt][nt][3]);
                *(uint2*)&Vt[((size_t)(bb * NKVH + kvh) * HD + d) * SEQ + spos] = v;
            }
        }
    }
}

// ---------------------------------------------------------------------------
// O projection: C[M,N] = A[M,K] @ W[N,K]^T, fp32 out. BK=64, swapped operands
// -> lane owns 4 consecutive n -> float4 stores. XCD swizzle: 2 n-tiles/xcd.
// ---------------------------------------------------------------------------
__global__ __launch_bounds__(256) void gemm_bt(const u16* __restrict__ A,
                                               const u16* __restrict__ W,
                                               float* __restrict__ C,
                                               int M, int N, int K) {
    const int bid = blockIdx.x;
    const int xcd = bid & 7, loc = bid >> 3;   // 64 locals per xcd
    const int n0 = (xcd * 2 + (loc & 1)) * 128;
    const int m0 = (loc >> 1) * 128;

    __shared__ __align__(16) u16 As[128 * 64];
    __shared__ __align__(16) u16 Ws[128 * 64];
    const int tid = threadIdx.x;
    const int lane = tid & 63, wave = tid >> 6;
    const int ar = lane & 15, quad = lane >> 4;
    const int q4 = quad * 4;
    const int wm = (wave >> 1) * 64, wn = (wave & 1) * 64;

    f32x4 acc[4][4] = {};

    for (int k0 = 0; k0 < K; k0 += 64) {
#pragma unroll
        for (int it = 0; it < 4; ++it) {
            const int ci = it * 256 + tid;
            const int row = ci >> 3, kcl = ci & 7;
            const int kcg = kcl ^ (row & 7);
            gload_lds16(&A[(size_t)(m0 + row) * K + k0 + kcg * 8], &As[ci * 8]);
            gload_lds16(&W[(size_t)(n0 + row) * K + k0 + kcg * 8], &Ws[ci * 8]);
        }
        __syncthreads();
#pragma unroll
        for (int kh = 0; kh < 2; ++kh) {
            bf16x8 af[4], bf[4];
#pragma unroll
            for (int t = 0; t < 4; ++t) {
                const int ra = wm + t * 16 + ar;
                af[t] = *(const bf16x8*)&As[ra * 64 + (((kh * 4 + quad) ^ (ra & 7))) * 8];
                const int rb = wn + t * 16 + ar;
                bf[t] = *(const bf16x8*)&Ws[rb * 64 + (((kh * 4 + quad) ^ (rb & 7))) * 8];
            }
#pragma unroll
            for (int mt = 0; mt < 4; ++mt)
#pragma unroll
                for (int nt = 0; nt < 4; ++nt)
                    acc[mt][nt] = MFMA_BF16(bf[nt], af[mt], acc[mt][nt]);  // C^T
        }
        __syncthreads();
    }

    // C^T regs: acc[mt][nt][r] = C[m0+wm+mt*16+ar][n0+wn+nt*16+q4+r]
#pragma unroll
    for (int mt = 0; mt < 4; ++mt) {
        const int t = m0 + wm + mt * 16 + ar;
#pragma unroll
        for (int nt = 0; nt < 4; ++nt) {
            float4 v = {acc[mt][nt][0], acc[mt][nt][1], acc[mt][nt][2], acc[mt][nt][3]};
            *(float4*)&C[(size_t)t * N + n0 + wn + nt * 16 + q4] = v;
        }
    }
}

// ---------------------------------------------------------------------------
// Flash attention, S^T formulation, causal-balanced: block p handles q-tiles
// p and 15-p (uniform 34 kv-iters). 128 q rows per phase, 32/wave.
// S^T = K*Q^T (lane owns q); O^T = V^T*P^T (own post-exp regs ARE the P^T
// B-frag under the kv relabeling baked into Vt). Max-free streaming softmax.
// ---------------------------------------------------------------------------
__global__ __launch_bounds__(256, 2) void flash_attn_mfma(
    const u16* __restrict__ Qg, const u16* __restrict__ Kg,
    const u16* __restrict__ Vtg, u16* __restrict__ AO) {
    const int p = blockIdx.x, h = blockIdx.y, b = blockIdx.z;
    const int kvh = h / GQ;
    const int tid = threadIdx.x;
    const int lane = tid & 63, w = tid >> 6;
    const int n = lane & 15, quad = lane >> 4;

    __shared__ __align__(16) u16 Qs[128 * 64];
    __shared__ __align__(16) u16 Ks[2 * 64 * 64];
    __shared__ __align__(16) u16 Vts[2 * 64 * 64];

    for (int ph = 0; ph < 2; ++ph) {
        const int bq = ph ? (15 - p) : p;
        const int q0 = bq * 128;

        // stage Q (128x64) and K/V tile 0 into buffer 0 (chunk ^= row&7)
#pragma unroll
        for (int it = 0; it < 4; ++it) {
            const int ci = it * 256 + tid;
            const int row = ci >> 3, kcg = (ci & 7) ^ (row & 7);
            gload_lds16(&Qg[(size_t)((b * SEQ + q0 + row) * NH + h) * HD + kcg * 8],
                        &Qs[ci * 8]);
        }
#pragma unroll
        for (int it = 0; it < 2; ++it) {
            const int ci = it * 256 + tid;
            const int row = ci >> 3, kcg = (ci & 7) ^ (row & 7);
            gload_lds16(&Kg[(size_t)((b * SEQ + row) * NKVH + kvh) * HD + kcg * 8],
                        &Ks[ci * 8]);
            gload_lds16(&Vtg[(size_t)((b * NKVH + kvh) * HD + row) * SEQ + kcg * 8],
                        &Vts[ci * 8]);
        }
        __syncthreads();

        // hoist Q^T B-frags
        bf16x8 Qf[2][2];
#pragma unroll
        for (int t = 0; t < 2; ++t)
#pragma unroll
            for (int kh = 0; kh < 2; ++kh) {
                const int qrow = w * 32 + t * 16 + n;
                const int c = (kh * 4 + quad) ^ (qrow & 7);
                Qf[t][kh] = *(const bf16x8*)&Qs[qrow * 64 + c * 8];
            }

        f32x4 O[2][4] = {};
        float lsum[2] = {0.f, 0.f};

        const int ktmax = 2 * bq + 1;
        for (int kt = 0; kt <= ktmax; ++kt) {
            const int cur = kt & 1;
            if (kt < ktmax) {  // prefetch next K/V tile into other buffer
                const int base = (cur ^ 1) * 4096;
#pragma unroll
                for (int it = 0; it < 2; ++it) {
                    const int ci = it * 256 + tid;
                    const int row = ci >> 3, kcg = (ci & 7) ^ (row & 7);
                    gload_lds16(&Kg[(size_t)((b * SEQ + (kt + 1) * 64 + row) * NKVH + kvh) * HD + kcg * 8],
                                &Ks[base + ci * 8]);
                    gload_lds16(&Vtg[(size_t)((b * NKVH + kvh) * HD + row) * SEQ + (kt + 1) * 64 + kcg * 8],
                                &Vts[base + ci * 8]);
                }
            }
            const u16* Kl = &Ks[cur * 4096];
            const u16* Vl = &Vts[cur * 4096];

            // S^T (log2-scaled domain; Q pre-scaled)
            f32x4 sc[2][4] = {};
#pragma unroll
            for (int kh = 0; kh < 2; ++kh)
#pragma unroll
                for (int k4 = 0; k4 < 4; ++k4) {
                    const int krow = k4 * 16 + n;
                    const int c = (kh * 4 + quad) ^ (krow & 7);
                    const bf16x8 Kf = *(const bf16x8*)&Kl[krow * 64 + c * 8];
                    sc[0][k4] = MFMA_BF16(Kf, Qf[0][kh], sc[0][k4]);
                    sc[1][k4] = MFMA_BF16(Kf, Qf[1][kh], sc[1][k4]);
                }

            const bool masked = (kt >= 2 * bq);
            bf16x8 Pf[2][2];
#pragma unroll
            for (int t = 0; t < 2; ++t) {
                const int qg = q0 + w * 32 + t * 16 + n;
                if (masked) {
#pragma unroll
                    for (int k4 = 0; k4 < 4; ++k4)
#pragma unroll
                        for (int r = 0; r < 4; ++r)
                            if (kt * 64 + k4 * 16 + quad * 4 + r > qg)
                                sc[t][k4][r] = -1e30f;  // exp2 -> 0
                }
                float sk[4];
#pragma unroll
                for (int k4 = 0; k4 < 4; ++k4) {
                    const float e0 = exp2f(sc[t][k4][0]);
                    const float e1 = exp2f(sc[t][k4][1]);
                    const float e2 = exp2f(sc[t][k4][2]);
                    const float e3 = exp2f(sc[t][k4][3]);
                    sc[t][k4][0] = e0; sc[t][k4][1] = e1;
                    sc[t][k4][2] = e2; sc[t][k4][3] = e3;
                    sk[k4] = (e0 + e1) + (e2 + e3);
                }
                lsum[t] += (sk[0] + sk[1]) + (sk[2] + sk[3]);
#pragma unroll
                for (int kb = 0; kb < 2; ++kb) {
                    union { u32 uw[4]; bf16x8 v; } cv;
#pragma unroll
                    for (int a = 0; a < 2; ++a) {
                        cv.uw[a * 2 + 0] = pack2r(sc[t][2 * kb + a][0], sc[t][2 * kb + a][1]);
                        cv.uw[a * 2 + 1] = pack2r(sc[t][2 * kb + a][2], sc[t][2 * kb + a][3]);
                    }
                    Pf[t][kb] = cv.v;
                }
            }

            // O^T += V^T * P^T
#pragma unroll
            for (int kb = 0; kb < 2; ++kb)
#pragma unroll
                for (int dt = 0; dt < 4; ++dt) {
                    const int drow = dt * 16 + n;
                    const int c = (kb * 4 + quad) ^ (drow & 7);
                    const bf16x8 Vf = *(const bf16x8*)&Vl[drow * 64 + c * 8];
                    O[0][dt] = MFMA_BF16(Vf, Pf[0][kb], O[0][dt]);
                    O[1][dt] = MFMA_BF16(Vf, Pf[1][kb], O[1][dt]);
                }
            __syncthreads();
        }

        // epilogue: reduce l across quads once; O^T regs: d=dt*16+quad*4+r, q=n
#pragma unroll
        for (int t = 0; t < 2; ++t) {
            float rs = lsum[t];
            rs += __shfl_xor(rs, 16, 64);
            rs += __shfl_xor(rs, 32, 64);
            const int qg = q0 + w * 32 + t * 16 + n;
            const float inv = 1.f / rs;
#pragma unroll
            for (int dt = 0; dt < 4; ++dt) {
                uint2 v2;
                v2.x = pack2r(O[t][dt][0] * inv, O[t][dt][1] * inv);
                v2.y = pack2r(O[t][dt][2] * inv, O[t][dt][3] * inv);
                *(uint2*)&AO[(size_t)((b * SEQ + qg) * NH + h) * HD + dt * 16 + quad * 4] = v2;
            }
        }
    }
}

// ---------------------------------------------------------------------------
extern "C" void kernel_launch(void* const* d_in, const int* in_sizes, int n_in,
                              void* d_out, int out_size, void* d_ws,
                              size_t ws_size, hipStream_t stream) {
    const float* hs = (const float*)d_in[0];
    const float* cosp = (const float*)d_in[1];
    const float* sinp = (const float*)d_in[2];
    // d_in[3] attention_mask: pure causal, handled in-kernel
    const float* Wq = (const float*)d_in[4];
    const float* Wk = (const float*)d_in[5];
    const float* Wv = (const float*)d_in[6];
    const float* Wo = (const float*)d_in[7];
    float* out = (float*)d_out;

    u16* ws = (u16*)d_ws;
    u16* hs_bf = ws;
    u16* Wq_bf = hs_bf + (size_t)4096 * 2048;
    u16* Wk_bf = Wq_bf + (size_t)2048 * 2048;
    u16* Wv_bf = Wk_bf + (size_t)512 * 2048;
    u16* Wo_bf = Wv_bf + (size_t)512 * 2048;
    u16* Qb = Wo_bf + (size_t)2048 * 2048;
    u16* Kb = Qb + (size_t)4096 * 2048;
    u16* Vt = Kb + (size_t)4096 * 512;
    u16* AO = hs_bf;  // alias: hs_bf dead after QKV projection

    cast_all<<<dim3(9216), 256, 0, stream>>>(hs, Wq, Wk, Wv, Wo, hs_bf, Wq_bf,
                                             Wk_bf, Wv_bf, Wo_bf);

    qkv_gemm<<<dim3(768), 256, 0, stream>>>(hs_bf, Wq_bf, Wk_bf, Wv_bf, Qb,
                                            Kb, Vt, cosp, sinp);

    flash_attn_mfma<<<dim3(8, NH, BATCH), 256, 0, stream>>>(Qb, Kb, Vt, AO);

    gemm_bt<<<dim3(512), 256, 0, stream>>>(AO, Wo_bf, out, 4096, 2048, 2048);
}